// Round 1
// baseline (3894.417 us; speedup 1.0000x reference)
//
#include <hip/hip_runtime.h>

#define HDIM 256

// ---------------- CSR build ----------------

__global__ void k_zero_int(int* p, int n) {
    int i = blockIdx.x * blockDim.x + threadIdx.x;
    if (i < n) p[i] = 0;
}

__global__ void k_hist(const int* __restrict__ src, const int* __restrict__ dst,
                       int E, int* __restrict__ deg) {
    int e = blockIdx.x * blockDim.x + threadIdx.x;
    if (e >= E) return;
    atomicAdd(&deg[dst[e]], 1);
    atomicAdd(&deg[src[e]], 1);
}

// exclusive scan, 1024 elems per block (256 thr x 4)
__global__ void k_scan_partial(const int* __restrict__ deg, int* __restrict__ rp,
                               int* __restrict__ bsum, int n) {
    __shared__ int sd[256];
    int t = threadIdx.x;
    int base = blockIdx.x * 1024 + t * 4;
    int v[4]; int tsum = 0;
    #pragma unroll
    for (int k = 0; k < 4; k++) { v[k] = (base + k < n) ? deg[base + k] : 0; tsum += v[k]; }
    sd[t] = tsum; __syncthreads();
    for (int off = 1; off < 256; off <<= 1) {
        int x = (t >= off) ? sd[t - off] : 0;
        __syncthreads();
        sd[t] += x;
        __syncthreads();
    }
    int run = sd[t] - tsum;   // exclusive prefix of this thread
    if (t == 255) bsum[blockIdx.x] = sd[255];
    #pragma unroll
    for (int k = 0; k < 4; k++) { if (base + k < n) rp[base + k] = run; run += v[k]; }
}

// single-block exclusive scan of up to 1024 partials, in place
__global__ void k_scan_bsum(int* __restrict__ bsum, int nb) {
    __shared__ int sd[256];
    int t = threadIdx.x;
    int base = t * 4;
    int v[4]; int tsum = 0;
    #pragma unroll
    for (int k = 0; k < 4; k++) { v[k] = (base + k < nb) ? bsum[base + k] : 0; tsum += v[k]; }
    sd[t] = tsum; __syncthreads();
    for (int off = 1; off < 256; off <<= 1) {
        int x = (t >= off) ? sd[t - off] : 0;
        __syncthreads();
        sd[t] += x;
        __syncthreads();
    }
    int run = sd[t] - tsum;
    #pragma unroll
    for (int k = 0; k < 4; k++) { if (base + k < nb) bsum[base + k] = run; run += v[k]; }
}

__global__ void k_scan_add(int* __restrict__ rp, int* __restrict__ cursor,
                           const int* __restrict__ bsum, int n, int twoE) {
    int i = blockIdx.x * blockDim.x + threadIdx.x;
    if (i < n) {
        int v = rp[i] + bsum[i >> 10];
        rp[i] = v;
        cursor[i] = v;
    }
    if (i == 0) rp[n] = twoE;
}

__global__ void k_fill(const int* __restrict__ src, const int* __restrict__ dst,
                       int E, int* __restrict__ cursor, int* __restrict__ col) {
    int e = blockIdx.x * blockDim.x + threadIdx.x;
    if (e >= E) return;
    int s = src[e], d = dst[e];
    int p = atomicAdd(&cursor[d], 1); col[p] = s;
    int q = atomicAdd(&cursor[s], 1); col[q] = d;
}

// ---------------- embed + GEMM0 (88 -> 256) ----------------
// 32 nodes per block, 256 threads; thread t owns output column t.

__global__ __launch_bounds__(256) void k_embed_gemm0(
    const int* __restrict__ atom,
    const float* __restrict__ eE, const float* __restrict__ eD,
    const float* __restrict__ eV, const float* __restrict__ eC,
    const float* __restrict__ eA, const float* __restrict__ eH,
    const float* __restrict__ eHy,
    const float* __restrict__ W0, const float* __restrict__ b0,
    float* __restrict__ x, int n) {
    __shared__ float f[32][88];
    int t = threadIdx.x;
    int node0 = blockIdx.x * 32;
    for (int idx = t; idx < 32 * 88; idx += 256) {
        int i = idx / 88, k = idx - 88 * i;
        int node = node0 + i;
        float val = 0.f;
        if (node < n) {
            const int* a = atom + (size_t)node * 7;
            if (k < 64)       val = eE[a[0] * 64 + k];
            else if (k < 68)  val = eD[a[1] * 4 + (k - 64)];
            else if (k < 72)  val = eV[(a[2] + 1) * 4 + (k - 68)];
            else if (k < 76)  val = eC[a[3] * 4 + (k - 72)];
            else if (k < 80)  val = eA[a[4] * 4 + (k - 76)];
            else if (k < 84)  val = eH[a[5] * 4 + (k - 80)];
            else              val = eHy[a[6] * 4 + (k - 84)];
        }
        f[i][k] = val;
    }
    __syncthreads();
    float acc[32];
    #pragma unroll
    for (int i = 0; i < 32; i++) acc[i] = 0.f;
    for (int k = 0; k < 88; k += 4) {
        float w0 = W0[(k + 0) * HDIM + t];
        float w1 = W0[(k + 1) * HDIM + t];
        float w2 = W0[(k + 2) * HDIM + t];
        float w3 = W0[(k + 3) * HDIM + t];
        #pragma unroll
        for (int i = 0; i < 32; i++) {
            float4 fv = *(const float4*)&f[i][k];
            acc[i] = fmaf(fv.x, w0, acc[i]);
            acc[i] = fmaf(fv.y, w1, acc[i]);
            acc[i] = fmaf(fv.z, w2, acc[i]);
            acc[i] = fmaf(fv.w, w3, acc[i]);
        }
    }
    float bb = b0[t];
    #pragma unroll
    for (int i = 0; i < 32; i++) {
        int node = node0 + i;
        if (node < n) x[(size_t)node * HDIM + t] = acc[i] + bb;
    }
}

// ---------------- gather + relu + segment-sum (pull via CSR) ----------------
// one wave (64 lanes) per node, 4 floats per lane (float4), 4 nodes per block

__global__ __launch_bounds__(256) void k_aggregate(
    const float* __restrict__ x, const int* __restrict__ rp,
    const int* __restrict__ col, const float* __restrict__ We,
    const float* __restrict__ be, float* __restrict__ z, int n) {
    int wid = threadIdx.x >> 6;
    int lane = threadIdx.x & 63;
    int node = blockIdx.x * 4 + wid;
    if (node >= n) return;
    const float4* x4 = (const float4*)x;
    float4 wv = ((const float4*)We)[lane];
    float4 bv = ((const float4*)be)[lane];
    float cx = wv.x + bv.x, cy = wv.y + bv.y, cz = wv.z + bv.z, cw = wv.w + bv.w;
    float4 a = x4[(size_t)node * 64 + lane];
    int p0 = rp[node], p1 = rp[node + 1];
    for (int p = p0; p < p1; p++) {
        int s = col[p];
        float4 v = x4[(size_t)s * 64 + lane];
        a.x += fmaxf(v.x + cx, 0.f);
        a.y += fmaxf(v.y + cy, 0.f);
        a.z += fmaxf(v.z + cz, 0.f);
        a.w += fmaxf(v.w + cw, 0.f);
    }
    ((float4*)z)[(size_t)node * 64 + lane] = a;
}

// ---------------- GEMM(256->256) [+ bias] [+ LayerNorm] ----------------
// 32 nodes per block in LDS; thread t owns output column t; fp32 accumulate.
// In-place safe (rows staged to LDS before any store).

template <bool DO_LN>
__global__ __launch_bounds__(256) void k_gemm(
    const float* __restrict__ zin, const float* __restrict__ W,
    const float* __restrict__ b, const float* __restrict__ g,
    const float* __restrict__ bt, float* __restrict__ xout, int n) {
    __shared__ float zs[32][HDIM];
    int t = threadIdx.x;
    int node0 = blockIdx.x * 32;
    #pragma unroll
    for (int i = 0; i < 32; i++) {
        int node = node0 + i;
        zs[i][t] = (node < n) ? zin[(size_t)node * HDIM + t] : 0.f;
    }
    __syncthreads();
    float acc[32];
    #pragma unroll
    for (int i = 0; i < 32; i++) acc[i] = 0.f;
    for (int k = 0; k < HDIM; k += 4) {
        float w0 = W[(k + 0) * HDIM + t];
        float w1 = W[(k + 1) * HDIM + t];
        float w2 = W[(k + 2) * HDIM + t];
        float w3 = W[(k + 3) * HDIM + t];
        #pragma unroll
        for (int i = 0; i < 32; i++) {
            float4 zv = *(const float4*)&zs[i][k];
            acc[i] = fmaf(zv.x, w0, acc[i]);
            acc[i] = fmaf(zv.y, w1, acc[i]);
            acc[i] = fmaf(zv.z, w2, acc[i]);
            acc[i] = fmaf(zv.w, w3, acc[i]);
        }
    }
    float bb = b[t];
    if (!DO_LN) {
        #pragma unroll
        for (int i = 0; i < 32; i++) {
            int node = node0 + i;
            if (node < n) xout[(size_t)node * HDIM + t] = acc[i] + bb;
        }
        return;
    }
    __syncthreads();
    #pragma unroll
    for (int i = 0; i < 32; i++) zs[i][t] = acc[i] + bb;
    __syncthreads();
    int wid = t >> 6, lane = t & 63;
    #pragma unroll
    for (int ii = 0; ii < 8; ii++) {
        int i = wid * 8 + ii;
        float v0 = zs[i][lane];
        float v1 = zs[i][lane + 64];
        float v2 = zs[i][lane + 128];
        float v3 = zs[i][lane + 192];
        float s = v0 + v1 + v2 + v3;
        float q = v0 * v0 + v1 * v1 + v2 * v2 + v3 * v3;
        #pragma unroll
        for (int off = 32; off >= 1; off >>= 1) {
            s += __shfl_xor(s, off, 64);
            q += __shfl_xor(q, off, 64);
        }
        float m = s * (1.f / 256.f);
        float var = q * (1.f / 256.f) - m * m;
        float inv = rsqrtf(var + 1e-5f);
        int node = node0 + i;
        if (node < n) {
            xout[(size_t)node * HDIM + lane      ] = (v0 - m) * inv * g[lane      ] + bt[lane      ];
            xout[(size_t)node * HDIM + lane + 64 ] = (v1 - m) * inv * g[lane + 64 ] + bt[lane + 64 ];
            xout[(size_t)node * HDIM + lane + 128] = (v2 - m) * inv * g[lane + 128] + bt[lane + 128];
            xout[(size_t)node * HDIM + lane + 192] = (v3 - m) * inv * g[lane + 192] + bt[lane + 192];
        }
    }
}

// ---------------- host ----------------

extern "C" void kernel_launch(void* const* d_in, const int* in_sizes, int n_in,
                              void* d_out, int out_size, void* d_ws, size_t ws_size,
                              hipStream_t stream) {
    const int*   atom = (const int*)d_in[0];
    const int*   src  = (const int*)d_in[1];
    const int*   dst  = (const int*)d_in[2];
    const float* eE   = (const float*)d_in[3];
    const float* eD   = (const float*)d_in[4];
    const float* eV   = (const float*)d_in[5];
    const float* eC   = (const float*)d_in[6];
    const float* eA   = (const float*)d_in[7];
    const float* eH   = (const float*)d_in[8];
    const float* eHy  = (const float*)d_in[9];
    const float* W0   = (const float*)d_in[10];
    const float* b0   = (const float*)d_in[11];
    const float* W1   = (const float*)d_in[12];
    const float* b1   = (const float*)d_in[13];

    const int N = in_sizes[0] / 7;
    const int E = in_sizes[1];
    const int twoE = 2 * E;

    float* x = (float*)d_out;             // N x 256, doubles as ping buffer

    // workspace carve
    float* z       = (float*)d_ws;        // N x 256
    int*   rp      = (int*)(z + (size_t)N * HDIM);   // N+1
    int*   cursor  = rp + (N + 1);        // N
    int*   deg     = cursor + N;          // N
    int*   col     = deg + N;             // 2E
    int*   bsum    = col + twoE;          // <=1024

    const int nb = (N + 1023) / 1024;     // partial-scan blocks (196)

    // CSR build
    k_zero_int<<<(N + 255) / 256, 256, 0, stream>>>(deg, N);
    k_hist<<<(E + 255) / 256, 256, 0, stream>>>(src, dst, E, deg);
    k_scan_partial<<<nb, 256, 0, stream>>>(deg, rp, bsum, N);
    k_scan_bsum<<<1, 256, 0, stream>>>(bsum, nb);
    k_scan_add<<<(N + 255) / 256, 256, 0, stream>>>(rp, cursor, bsum, N, twoE);
    k_fill<<<(E + 255) / 256, 256, 0, stream>>>(src, dst, E, cursor, col);

    // embed + first GEMM
    const int nblk32 = (N + 31) / 32;
    k_embed_gemm0<<<nblk32, 256, 0, stream>>>(atom, eE, eD, eV, eC, eA, eH, eHy,
                                              W0, b0, x, N);

    // 4 GINE layers
    const int nblk4 = (N + 3) / 4;
    for (int L = 0; L < 4; L++) {
        const float* Wn = (const float*)d_in[14 + 6 * L + 0];
        const float* bn = (const float*)d_in[14 + 6 * L + 1];
        const float* We = (const float*)d_in[14 + 6 * L + 2];
        const float* be = (const float*)d_in[14 + 6 * L + 3];
        const float* g  = (const float*)d_in[14 + 6 * L + 4];
        const float* bt = (const float*)d_in[14 + 6 * L + 5];
        k_aggregate<<<nblk4, 256, 0, stream>>>(x, rp, col, We, be, z, N);
        k_gemm<true><<<nblk32, 256, 0, stream>>>(z, Wn, bn, g, bt, x, N);
    }

    // final projection (in-place on d_out)
    k_gemm<false><<<nblk32, 256, 0, stream>>>(x, W1, b1, nullptr, nullptr, x, N);
}

// Round 2
// 1782.923 us; speedup vs baseline: 2.1843x; 2.1843x over previous
//
#include <hip/hip_runtime.h>

#define HDIM 256

typedef __attribute__((ext_vector_type(8))) short short8;
typedef __attribute__((ext_vector_type(4))) float f32x4;

__device__ __forceinline__ unsigned short f2bf(float f) {
    unsigned int u = __float_as_uint(f);
    u += 0x7FFF + ((u >> 16) & 1);   // round-to-nearest-even
    return (unsigned short)(u >> 16);
}

// ---------------- CSR build ----------------

__global__ void k_zero_int(int* p, int n) {
    int i = blockIdx.x * blockDim.x + threadIdx.x;
    if (i < n) p[i] = 0;
}

__global__ void k_hist(const int* __restrict__ src, const int* __restrict__ dst,
                       int E, int* __restrict__ deg) {
    int e = blockIdx.x * blockDim.x + threadIdx.x;
    if (e >= E) return;
    atomicAdd(&deg[dst[e]], 1);
    atomicAdd(&deg[src[e]], 1);
}

__global__ void k_scan_partial(const int* __restrict__ deg, int* __restrict__ rp,
                               int* __restrict__ bsum, int n) {
    __shared__ int sd[256];
    int t = threadIdx.x;
    int base = blockIdx.x * 1024 + t * 4;
    int v[4]; int tsum = 0;
    #pragma unroll
    for (int k = 0; k < 4; k++) { v[k] = (base + k < n) ? deg[base + k] : 0; tsum += v[k]; }
    sd[t] = tsum; __syncthreads();
    for (int off = 1; off < 256; off <<= 1) {
        int x = (t >= off) ? sd[t - off] : 0;
        __syncthreads();
        sd[t] += x;
        __syncthreads();
    }
    int run = sd[t] - tsum;
    if (t == 255) bsum[blockIdx.x] = sd[255];
    #pragma unroll
    for (int k = 0; k < 4; k++) { if (base + k < n) rp[base + k] = run; run += v[k]; }
}

__global__ void k_scan_bsum(int* __restrict__ bsum, int nb) {
    __shared__ int sd[256];
    int t = threadIdx.x;
    int base = t * 4;
    int v[4]; int tsum = 0;
    #pragma unroll
    for (int k = 0; k < 4; k++) { v[k] = (base + k < nb) ? bsum[base + k] : 0; tsum += v[k]; }
    sd[t] = tsum; __syncthreads();
    for (int off = 1; off < 256; off <<= 1) {
        int x = (t >= off) ? sd[t - off] : 0;
        __syncthreads();
        sd[t] += x;
        __syncthreads();
    }
    int run = sd[t] - tsum;
    #pragma unroll
    for (int k = 0; k < 4; k++) { if (base + k < nb) bsum[base + k] = run; run += v[k]; }
}

__global__ void k_scan_add(int* __restrict__ rp, int* __restrict__ cursor,
                           const int* __restrict__ bsum, int n, int twoE) {
    int i = blockIdx.x * blockDim.x + threadIdx.x;
    if (i < n) {
        int v = rp[i] + bsum[i >> 10];
        rp[i] = v;
        cursor[i] = v;
    }
    if (i == 0) rp[n] = twoE;
}

__global__ void k_fill(const int* __restrict__ src, const int* __restrict__ dst,
                       int E, int* __restrict__ cursor, int* __restrict__ col) {
    int e = blockIdx.x * blockDim.x + threadIdx.x;
    if (e >= E) return;
    int s = src[e], d = dst[e];
    int p = atomicAdd(&cursor[d], 1); col[p] = s;
    int q = atomicAdd(&cursor[s], 1); col[q] = d;
}

// ---------------- weight transpose + bf16 convert ----------------
// Wt[n][k] = bf16(W[k][n]); one W per launch. grid=256 (k), block=256 (n)

__global__ void k_prep_w(const float* __restrict__ W, unsigned short* __restrict__ Wt) {
    int k = blockIdx.x, nn = threadIdx.x;
    Wt[nn * 256 + k] = f2bf(W[k * 256 + nn]);
}

// ---------------- embed + GEMM0 (88 -> 256), fp32 ----------------

__global__ __launch_bounds__(256) void k_embed_gemm0(
    const int* __restrict__ atom,
    const float* __restrict__ eE, const float* __restrict__ eD,
    const float* __restrict__ eV, const float* __restrict__ eC,
    const float* __restrict__ eA, const float* __restrict__ eH,
    const float* __restrict__ eHy,
    const float* __restrict__ W0, const float* __restrict__ b0,
    float* __restrict__ x, int n) {
    __shared__ float f[32][88];
    int t = threadIdx.x;
    int node0 = blockIdx.x * 32;
    for (int idx = t; idx < 32 * 88; idx += 256) {
        int i = idx / 88, k = idx - 88 * i;
        int node = node0 + i;
        float val = 0.f;
        if (node < n) {
            const int* a = atom + (size_t)node * 7;
            if (k < 64)       val = eE[a[0] * 64 + k];
            else if (k < 68)  val = eD[a[1] * 4 + (k - 64)];
            else if (k < 72)  val = eV[(a[2] + 1) * 4 + (k - 68)];
            else if (k < 76)  val = eC[a[3] * 4 + (k - 72)];
            else if (k < 80)  val = eA[a[4] * 4 + (k - 76)];
            else if (k < 84)  val = eH[a[5] * 4 + (k - 80)];
            else              val = eHy[a[6] * 4 + (k - 84)];
        }
        f[i][k] = val;
    }
    __syncthreads();
    float acc[32];
    #pragma unroll
    for (int i = 0; i < 32; i++) acc[i] = 0.f;
    for (int k = 0; k < 88; k += 4) {
        float w0 = W0[(k + 0) * HDIM + t];
        float w1 = W0[(k + 1) * HDIM + t];
        float w2 = W0[(k + 2) * HDIM + t];
        float w3 = W0[(k + 3) * HDIM + t];
        #pragma unroll
        for (int i = 0; i < 32; i++) {
            float4 fv = *(const float4*)&f[i][k];
            acc[i] = fmaf(fv.x, w0, acc[i]);
            acc[i] = fmaf(fv.y, w1, acc[i]);
            acc[i] = fmaf(fv.z, w2, acc[i]);
            acc[i] = fmaf(fv.w, w3, acc[i]);
        }
    }
    float bb = b0[t];
    #pragma unroll
    for (int i = 0; i < 32; i++) {
        int node = node0 + i;
        if (node < n) x[(size_t)node * HDIM + t] = acc[i] + bb;
    }
}

// ---------------- gather + relu + segment-sum (pull via CSR) ----------------

__global__ __launch_bounds__(256) void k_aggregate(
    const float* __restrict__ x, const int* __restrict__ rp,
    const int* __restrict__ col, const float* __restrict__ We,
    const float* __restrict__ be, float* __restrict__ z, int n) {
    int wid = threadIdx.x >> 6;
    int lane = threadIdx.x & 63;
    int node = blockIdx.x * 4 + wid;
    if (node >= n) return;
    const float4* x4 = (const float4*)x;
    float4 wv = ((const float4*)We)[lane];
    float4 bv = ((const float4*)be)[lane];
    float cx = wv.x + bv.x, cy = wv.y + bv.y, cz = wv.z + bv.z, cw = wv.w + bv.w;
    float4 a = x4[(size_t)node * 64 + lane];
    int p0 = rp[node], p1 = rp[node + 1];
    for (int p = p0; p < p1; p++) {
        int s = col[p];
        float4 v = x4[(size_t)s * 64 + lane];
        a.x += fmaxf(v.x + cx, 0.f);
        a.y += fmaxf(v.y + cy, 0.f);
        a.z += fmaxf(v.z + cz, 0.f);
        a.w += fmaxf(v.w + cw, 0.f);
    }
    ((float4*)z)[(size_t)node * 64 + lane] = a;
}

// ---------------- MFMA GEMM (256->256) [+ bias] [+ LayerNorm] ----------------
// Block: 256 threads = 4 waves; 64 rows x 256 cols. Wave w owns cols [64w, 64w+64).
// A staged fp32->bf16 in LDS with XOR swizzle; B read from pre-transposed bf16 Wt (L2).
// mfma_f32_16x16x32_bf16: A row=l&15,k=8*(l>>4)+i ; B col=l&15 ; D col=l&15,row=4*(l>>4)+reg.

template <bool DO_LN>
__global__ __launch_bounds__(256) void k_gemm_mfma(
    const float* __restrict__ zin, const unsigned short* __restrict__ Wt,
    const float* __restrict__ b, const float* __restrict__ g,
    const float* __restrict__ bt, float* __restrict__ xout, int n) {
    __shared__ unsigned short As[64 * 256];     // 32 KB, swizzled
    __shared__ float psum[4][64], psq[4][64];
    __shared__ float mean_s[64], inv_s[64];

    int t = threadIdx.x;
    size_t node0 = (size_t)blockIdx.x * 64;

    // ---- stage Z tile: 64 rows x 256 cols fp32 -> bf16 LDS (swizzled) ----
    const float4* zrow = (const float4*)(zin + node0 * HDIM);
    #pragma unroll
    for (int i = 0; i < 16; i++) {
        int g4 = i * 256 + t;            // float4 index within tile
        int row = g4 >> 6;
        int c4 = g4 & 63;
        float4 v = make_float4(0.f, 0.f, 0.f, 0.f);
        if (node0 + row < (size_t)n) v = zrow[g4];
        ushort4 h;
        h.x = f2bf(v.x); h.y = f2bf(v.y); h.z = f2bf(v.z); h.w = f2bf(v.w);
        int boff = (c4 << 3) ^ ((row & 7) << 4);
        *(ushort4*)((char*)As + row * 512 + boff) = h;
    }
    __syncthreads();

    int w  = t >> 6;        // wave id -> col block
    int l  = t & 63;
    int lr = l & 15;
    int lk = l >> 4;

    f32x4 acc[4][4];
    #pragma unroll
    for (int rg = 0; rg < 4; rg++)
        #pragma unroll
        for (int cg = 0; cg < 4; cg++)
            acc[rg][cg] = (f32x4){0.f, 0.f, 0.f, 0.f};

    #pragma unroll
    for (int kt = 0; kt < 8; kt++) {
        int kbyte = kt * 64 + lk * 16;
        short8 a[4], bf[4];
        #pragma unroll
        for (int rg = 0; rg < 4; rg++) {
            int row = rg * 16 + lr;
            a[rg] = *(const short8*)((const char*)As + row * 512 + (kbyte ^ ((row & 7) << 4)));
        }
        #pragma unroll
        for (int cg = 0; cg < 4; cg++) {
            int coln = w * 64 + cg * 16 + lr;
            bf[cg] = *(const short8*)((const char*)Wt + coln * 512 + kbyte);
        }
        #pragma unroll
        for (int rg = 0; rg < 4; rg++)
            #pragma unroll
            for (int cg = 0; cg < 4; cg++)
                acc[rg][cg] = __builtin_amdgcn_mfma_f32_16x16x32_bf16(a[rg], bf[cg], acc[rg][cg], 0, 0, 0);
    }

    // bias per column
    float bcol[4];
    #pragma unroll
    for (int cg = 0; cg < 4; cg++) bcol[cg] = b[w * 64 + cg * 16 + lr];
    #pragma unroll
    for (int rg = 0; rg < 4; rg++)
        #pragma unroll
        for (int cg = 0; cg < 4; cg++)
            #pragma unroll
            for (int j = 0; j < 4; j++) acc[rg][cg][j] += bcol[cg];

    if (!DO_LN) {
        #pragma unroll
        for (int rg = 0; rg < 4; rg++)
            #pragma unroll
            for (int j = 0; j < 4; j++) {
                int row = rg * 16 + lk * 4 + j;
                size_t node = node0 + row;
                if (node < (size_t)n) {
                    #pragma unroll
                    for (int cg = 0; cg < 4; cg++)
                        xout[node * HDIM + w * 64 + cg * 16 + lr] = acc[rg][cg][j];
                }
            }
        return;
    }

    // ---- fused LayerNorm ----
    float sv[4][4], sq[4][4];
    #pragma unroll
    for (int rg = 0; rg < 4; rg++)
        #pragma unroll
        for (int j = 0; j < 4; j++) {
            float s = 0.f, q = 0.f;
            #pragma unroll
            for (int cg = 0; cg < 4; cg++) {
                float v = acc[rg][cg][j];
                s += v; q += v * v;
            }
            sv[rg][j] = s; sq[rg][j] = q;
        }
    #pragma unroll
    for (int off = 1; off < 16; off <<= 1) {
        #pragma unroll
        for (int rg = 0; rg < 4; rg++)
            #pragma unroll
            for (int j = 0; j < 4; j++) {
                sv[rg][j] += __shfl_xor(sv[rg][j], off, 64);
                sq[rg][j] += __shfl_xor(sq[rg][j], off, 64);
            }
    }
    if (lr == 0) {
        #pragma unroll
        for (int rg = 0; rg < 4; rg++)
            #pragma unroll
            for (int j = 0; j < 4; j++) {
                int row = rg * 16 + lk * 4 + j;
                psum[w][row] = sv[rg][j];
                psq[w][row]  = sq[rg][j];
            }
    }
    __syncthreads();
    if (t < 64) {
        float s = psum[0][t] + psum[1][t] + psum[2][t] + psum[3][t];
        float q = psq[0][t] + psq[1][t] + psq[2][t] + psq[3][t];
        float m = s * (1.f / 256.f);
        float var = q * (1.f / 256.f) - m * m;
        mean_s[t] = m;
        inv_s[t]  = rsqrtf(var + 1e-5f);
    }
    __syncthreads();

    float gv[4], btv[4];
    #pragma unroll
    for (int cg = 0; cg < 4; cg++) {
        int coln = w * 64 + cg * 16 + lr;
        gv[cg] = g[coln]; btv[cg] = bt[coln];
    }
    #pragma unroll
    for (int rg = 0; rg < 4; rg++)
        #pragma unroll
        for (int j = 0; j < 4; j++) {
            int row = rg * 16 + lk * 4 + j;
            float m = mean_s[row];
            float inv = inv_s[row];
            size_t node = node0 + row;
            if (node < (size_t)n) {
                #pragma unroll
                for (int cg = 0; cg < 4; cg++)
                    xout[node * HDIM + w * 64 + cg * 16 + lr] =
                        (acc[rg][cg][j] - m) * inv * gv[cg] + btv[cg];
            }
        }
}

// ---------------- host ----------------

extern "C" void kernel_launch(void* const* d_in, const int* in_sizes, int n_in,
                              void* d_out, int out_size, void* d_ws, size_t ws_size,
                              hipStream_t stream) {
    const int*   atom = (const int*)d_in[0];
    const int*   src  = (const int*)d_in[1];
    const int*   dst  = (const int*)d_in[2];
    const float* eE   = (const float*)d_in[3];
    const float* eD   = (const float*)d_in[4];
    const float* eV   = (const float*)d_in[5];
    const float* eC   = (const float*)d_in[6];
    const float* eA   = (const float*)d_in[7];
    const float* eH   = (const float*)d_in[8];
    const float* eHy  = (const float*)d_in[9];
    const float* W0   = (const float*)d_in[10];
    const float* b0   = (const float*)d_in[11];
    const float* W1   = (const float*)d_in[12];
    const float* b1   = (const float*)d_in[13];

    const int N = in_sizes[0] / 7;
    const int E = in_sizes[1];
    const int twoE = 2 * E;

    float* x = (float*)d_out;

    // workspace carve
    float* z       = (float*)d_ws;                       // N x 256
    int*   rp      = (int*)(z + (size_t)N * HDIM);       // N+1
    int*   cursor  = rp + (N + 1);
    int*   deg     = cursor + N;
    int*   col     = deg + N;                            // 2E
    int*   bsum    = col + twoE;                         // <=1024
    uintptr_t pw = (uintptr_t)(bsum + 1024);
    pw = (pw + 255) & ~(uintptr_t)255;
    unsigned short* Wt = (unsigned short*)pw;            // 5 x 256 x 256 bf16

    const int nb = (N + 1023) / 1024;

    // CSR build
    k_zero_int<<<(N + 255) / 256, 256, 0, stream>>>(deg, N);
    k_hist<<<(E + 255) / 256, 256, 0, stream>>>(src, dst, E, deg);
    k_scan_partial<<<nb, 256, 0, stream>>>(deg, rp, bsum, N);
    k_scan_bsum<<<1, 256, 0, stream>>>(bsum, nb);
    k_scan_add<<<(N + 255) / 256, 256, 0, stream>>>(rp, cursor, bsum, N, twoE);
    k_fill<<<(E + 255) / 256, 256, 0, stream>>>(src, dst, E, cursor, col);

    // weight prep: Wn0..Wn3, W1 -> bf16 transposed
    for (int L = 0; L < 4; L++) {
        const float* Wn = (const float*)d_in[14 + 6 * L + 0];
        k_prep_w<<<256, 256, 0, stream>>>(Wn, Wt + (size_t)L * 65536);
    }
    k_prep_w<<<256, 256, 0, stream>>>(W1, Wt + (size_t)4 * 65536);

    // embed + first GEMM
    const int nblk32 = (N + 31) / 32;
    k_embed_gemm0<<<nblk32, 256, 0, stream>>>(atom, eE, eD, eV, eC, eA, eH, eHy,
                                              W0, b0, x, N);

    // 4 GINE layers
    const int nblk4 = (N + 3) / 4;
    const int nblk64 = (N + 63) / 64;
    for (int L = 0; L < 4; L++) {
        const float* bn = (const float*)d_in[14 + 6 * L + 1];
        const float* We = (const float*)d_in[14 + 6 * L + 2];
        const float* be = (const float*)d_in[14 + 6 * L + 3];
        const float* g  = (const float*)d_in[14 + 6 * L + 4];
        const float* bt = (const float*)d_in[14 + 6 * L + 5];
        k_aggregate<<<nblk4, 256, 0, stream>>>(x, rp, col, We, be, z, N);
        k_gemm_mfma<true><<<nblk64, 256, 0, stream>>>(z, Wt + (size_t)L * 65536,
                                                      bn, g, bt, x, N);
    }

    // final projection (in-place on d_out)
    k_gemm_mfma<false><<<nblk64, 256, 0, stream>>>(x, Wt + (size_t)4 * 65536,
                                                   b1, nullptr, nullptr, x, N);
}